// Round 1
// baseline (51.627 us; speedup 1.0000x reference)
//
#include <hip/hip_runtime.h>
#include <math.h>

#define DIM 16

__global__ __launch_bounds__(256) void quanv_fused_kernel(
    const float* __restrict__ x,     // [B, 784]  (28x28 per image)
    const float* __restrict__ wts,   // [2, 4]
    const float* __restrict__ W,     // [10, 784]
    const float* __restrict__ bias,  // [10]
    float* __restrict__ out,         // [B, 10]
    int B)
{
    __shared__ __align__(16) float Vl[DIM * DIM];   // Vl[j*16+i] = <i| V |j>
    __shared__ __align__(16) float px[784];
    __shared__ __align__(16) float feats[784];
    __shared__ float wcs[16];                       // cos/sin of weights/2
    __shared__ float partial[4][10];

    const int tid = threadIdx.x;
    const int img = blockIdx.x;
    if (img >= B) return;

    // --- cos/sin of variational weights (8 sincos per block, negligible) ---
    if (tid < 8) {
        float th = wts[tid] * 0.5f;   // wts is [2][4] row-major, tid = d*4+w
        float s, c;
        sincosf(th, &s, &c);
        wcs[tid * 2 + 0] = c;
        wcs[tid * 2 + 1] = s;
    }
    __syncthreads();

    // --- build fixed variational matrix V: column j = circuit applied to |j> ---
    if (tid < DIM) {
        float a[DIM];
#pragma unroll
        for (int i = 0; i < DIM; ++i) a[i] = (i == tid) ? 1.0f : 0.0f;
#pragma unroll
        for (int d = 0; d < 2; ++d) {
#pragma unroll
            for (int w = 0; w < 4; ++w) {
                float c = wcs[(d * 4 + w) * 2 + 0];
                float s = wcs[(d * 4 + w) * 2 + 1];
                const int m = 8 >> w;   // qubit w lives at bit (3-w)
#pragma unroll
                for (int i = 0; i < DIM; ++i) {
                    if (!(i & m)) {
                        float a0 = a[i], a1 = a[i | m];
                        a[i]     = c * a0 - s * a1;
                        a[i | m] = s * a0 + c * a1;
                    }
                }
            }
#pragma unroll
            for (int c = 0; c < 3; ++c) {   // CNOT (c, c+1)
                const int cm = 8 >> c, tm = 8 >> (c + 1);
#pragma unroll
                for (int i = 0; i < DIM; ++i) {
                    if ((i & cm) && !(i & tm)) {
                        float t = a[i]; a[i] = a[i | tm]; a[i | tm] = t;
                    }
                }
            }
        }
#pragma unroll
        for (int i = 0; i < DIM; ++i) Vl[tid * DIM + i] = a[i];
    }

    // --- coalesced load of this image's 784 pixels (196 x float4) ---
    if (tid < 196) {
        ((float4*)px)[tid] = ((const float4*)(x + (size_t)img * 784))[tid];
    }
    __syncthreads();

    // --- one patch per thread: product state -> y = V s -> <Z_w> ---
    if (tid < 196) {
        const int pi = tid / 14, pj = tid % 14;
        const int r = pi * 2, cc = pj * 2;
        float s0, c0, s1, c1, s2, c2, s3, c3;
        __sincosf(px[r * 28 + cc]           * 0.5f, &s0, &c0);
        __sincosf(px[r * 28 + cc + 1]       * 0.5f, &s1, &c1);
        __sincosf(px[(r + 1) * 28 + cc]     * 0.5f, &s2, &c2);
        __sincosf(px[(r + 1) * 28 + cc + 1] * 0.5f, &s3, &c3);

        // product state s[j] = p01[j>>2] * p23[j&3], j = q0*8+q1*4+q2*2+q3
        float p01[4] = {c0 * c1, c0 * s1, s0 * c1, s0 * s1};
        float p23[4] = {c2 * c3, c2 * s3, s2 * c3, s2 * s3};

        float y[DIM];
#pragma unroll
        for (int i = 0; i < DIM; ++i) y[i] = 0.0f;
#pragma unroll
        for (int j = 0; j < DIM; ++j) {
            float sj = p01[j >> 2] * p23[j & 3];
#pragma unroll
            for (int i = 0; i < DIM; ++i)
                y[i] = fmaf(Vl[j * DIM + i], sj, y[i]);   // LDS broadcast read
        }

        float f0 = 0.f, f1 = 0.f, f2 = 0.f, f3 = 0.f;
#pragma unroll
        for (int i = 0; i < DIM; ++i) {
            float yy = y[i] * y[i];
            f0 += (i & 8) ? -yy : yy;
            f1 += (i & 4) ? -yy : yy;
            f2 += (i & 2) ? -yy : yy;
            f3 += (i & 1) ? -yy : yy;
        }
        ((float4*)feats)[tid] = make_float4(f0, f1, f2, f3);
    }
    __syncthreads();

    // --- 784 x 10 dot products, strided across 256 threads ---
    float acc[10];
#pragma unroll
    for (int k = 0; k < 10; ++k) acc[k] = 0.0f;
    for (int idx = tid; idx < 784; idx += 256) {
        float fv = feats[idx];
#pragma unroll
        for (int k = 0; k < 10; ++k)
            acc[k] = fmaf(fv, W[k * 784 + idx], acc[k]);
    }
#pragma unroll
    for (int k = 0; k < 10; ++k) {
#pragma unroll
        for (int off = 32; off; off >>= 1)
            acc[k] += __shfl_down(acc[k], off, 64);
    }
    const int wave = tid >> 6, lane = tid & 63;
    if (lane == 0) {
#pragma unroll
        for (int k = 0; k < 10; ++k) partial[wave][k] = acc[k];
    }
    __syncthreads();

    // --- bias + log_softmax over 10 classes (trivial, thread 0) ---
    if (tid == 0) {
        float lg[10];
        float m = -1e30f;
#pragma unroll
        for (int k = 0; k < 10; ++k) {
            lg[k] = partial[0][k] + partial[1][k] + partial[2][k] + partial[3][k] + bias[k];
            m = fmaxf(m, lg[k]);
        }
        float sum = 0.0f;
#pragma unroll
        for (int k = 0; k < 10; ++k) sum += expf(lg[k] - m);
        float lse = m + logf(sum);
#pragma unroll
        for (int k = 0; k < 10; ++k) out[(size_t)img * 10 + k] = lg[k] - lse;
    }
}

extern "C" void kernel_launch(void* const* d_in, const int* in_sizes, int n_in,
                              void* d_out, int out_size, void* d_ws, size_t ws_size,
                              hipStream_t stream) {
    const float* x    = (const float*)d_in[0];
    const float* wts  = (const float*)d_in[1];
    const float* W    = (const float*)d_in[2];
    const float* bias = (const float*)d_in[3];
    float* out        = (float*)d_out;

    const int B = in_sizes[0] / 784;
    quanv_fused_kernel<<<B, 256, 0, stream>>>(x, wts, W, bias, out, B);
}

// Round 2
// 22.341 us; speedup vs baseline: 2.3109x; 2.3109x over previous
//
#include <hip/hip_runtime.h>
#include <math.h>

// Quanvolution via Pauli back-propagation.
// Circuit: RY(theta_q) RY(w0_q) -> CNOT(0,1)(1,2)(2,3) -> RY(w1_q) -> CNOTs, measure Z_w.
// Fuse alpha_q = theta_q + w0_q (same-axis rotations add). Conjugate Z_w backwards:
//   C2: Z0->Z0, Z1->Z0Z1, Z2->Z0Z1Z2, Z3->Z0Z1Z2Z3
//   L2: Z_q -> c_q Z_q - s_q X_q  (c_q=cos w1_q, s_q=sin w1_q; FULL angles)
//   C1: Z0->Z0, X0->X0X1, Z1->Z0Z1, X1->X1X2, Z2->Z0Z1Z2, X2->X2X3, Z3->Z0Z1Z2Z3, X3->X3
// On the product state: <Z_q>=cos a_q =: (A,B,C,D), <X_q>=sin a_q =: (a,b,c,d), <Y>=0.
// Surviving terms:
//  z0 = c0*A - s0*ab
//  z1 = c0c1*B - c0s1*Abc + s0s1*ac
//  z2 = c0c1c2*AC - c0c1s2*Bcd + c0s1s2*Abd - s0c1c2*abC - s0s1s2*ad
//  z3 = c0c1c2c3*BD - c0c1c2s3*ACd + c0c1s2s3*Bc - c0s1c2c3*AbcD - c0s1s2s3*Ab
//       + s0c1c2s3*abCd + s0s1c2c3*acD + s0s1s2s3*a
__global__ __launch_bounds__(256) void quanv4_kernel(
    const float* __restrict__ x,     // [B, 784]
    const float* __restrict__ wts,   // [2, 4]
    const float* __restrict__ W,     // [10, 784]
    const float* __restrict__ bias,  // [10]
    float* __restrict__ out,         // [B, 10]
    int B)
{
    __shared__ __align__(16) float feats[4][784];
    __shared__ __align__(16) float scs[16];       // cw0[4] sw0[4] cw1[4] sw1[4]
    __shared__ float part[4][8][12];
    __shared__ float logits[4][10];

    const int tid = threadIdx.x;
    const int img0 = blockIdx.x * 4;

    if (tid < 8) {
        float s, c;
        sincosf(wts[tid], &s, &c);                // FULL angle, accurate
        const int dd = tid >> 2, q = tid & 3;
        scs[dd * 8 + q]     = c;
        scs[dd * 8 + 4 + q] = s;
    }
    __syncthreads();

    const float4 cw0 = *(const float4*)&scs[0];
    const float4 sw0 = *(const float4*)&scs[4];
    const float4 cw1 = *(const float4*)&scs[8];
    const float4 sw1 = *(const float4*)&scs[12];

    // 18 signed coefficients (constants per launch, built per-thread: ~20 muls)
    const float cc = cw1.x*cw1.y, cs = cw1.x*sw1.y, sc = sw1.x*cw1.y, ss = sw1.x*sw1.y;
    const float ccc = cc*cw1.z, ccs = cc*sw1.z, csc = cs*cw1.z, css = cs*sw1.z;
    const float scc = sc*cw1.z, ssc = ss*cw1.z, sss = ss*sw1.z;
    const float K0 = cw1.x,     K1 = -sw1.x;
    const float K2 = cc,        K3 = -cs,        K4 = ss;
    const float K5 = ccc,       K6 = -ccs,       K7 = css,  K8 = -scc, K9 = -sss;
    const float L1 = ccc*cw1.w, L2 = -ccc*sw1.w, L3 = ccs*sw1.w, L4 = -csc*cw1.w;
    const float L5 = -css*sw1.w, L6 = scc*sw1.w, L7 = ssc*cw1.w, L8 = sss*sw1.w;

    // --- patch phase: 4 images x 196 patches over 256 threads ---
    for (int p = tid; p < 784; p += 256) {
        const int img = p / 196;
        const int pl  = p - img * 196;
        const int gimg = img0 + img;
        if (gimg >= B) break;
        const int pi = pl / 14, pj = pl - pi * 14;
        const float* xp = x + (size_t)gimg * 784 + pi * 56 + pj * 2;
        const float2 t0 = *(const float2*)xp;          // q0, q1
        const float2 t1 = *(const float2*)(xp + 28);   // q2, q3

        float sth, cth;
        __sincosf(t0.x, &sth, &cth);   // theta in [0,1): accurate fast path
        const float a = sth*cw0.x + cth*sw0.x, A  = cth*cw0.x - sth*sw0.x;
        __sincosf(t0.y, &sth, &cth);
        const float b = sth*cw0.y + cth*sw0.y, Bv = cth*cw0.y - sth*sw0.y;
        __sincosf(t1.x, &sth, &cth);
        const float c = sth*cw0.z + cth*sw0.z, C  = cth*cw0.z - sth*sw0.z;
        __sincosf(t1.y, &sth, &cth);
        const float d = sth*cw0.w + cth*sw0.w, D  = cth*cw0.w - sth*sw0.w;

        const float ab=a*b, bc=b*c, ac=a*c, cd=c*d, bd=b*d, ad=a*d;
        const float AC=A*C, Ab=A*b, Bc=Bv*c, BD=Bv*D, cD=c*D, Cd=C*d;

        const float z0 = K0*A  + K1*ab;
        const float z1 = K2*Bv + K3*(A*bc) + K4*ac;
        const float z2 = K5*AC + K6*(Bv*cd) + K7*(A*bd) + K8*(ab*C) + K9*ad;
        const float z3 = L1*BD + L2*(AC*d) + L3*Bc + L4*(Ab*cD) + L5*Ab
                       + L6*(ab*Cd) + L7*(ac*D) + L8*a;

        *(float4*)&feats[img][pl * 4] = make_float4(z0, z1, z2, z3);
    }
    __syncthreads();

    // --- GEMM phase: wave w owns image w; lane covers k = it*256 + lane*4 ---
    const int wave = tid >> 6, lane = tid & 63;
    if (img0 + wave < B) {
        float acc[10];
#pragma unroll
        for (int k10 = 0; k10 < 10; ++k10) acc[k10] = 0.f;
#pragma unroll
        for (int it = 0; it < 4; ++it) {
            const int k = it * 256 + lane * 4;
            if (k < 784) {
                const float4 f = *(const float4*)&feats[wave][k];
#pragma unroll
                for (int cl = 0; cl < 10; ++cl) {
                    const float4 wv = *(const float4*)&W[cl * 784 + k];
                    acc[cl] = fmaf(f.x, wv.x, fmaf(f.y, wv.y,
                              fmaf(f.z, wv.z, fmaf(f.w, wv.w, acc[cl]))));
                }
            }
        }
#pragma unroll
        for (int cl = 0; cl < 10; ++cl) {
            acc[cl] += __shfl_down(acc[cl], 32, 64);
            acc[cl] += __shfl_down(acc[cl], 16, 64);
            acc[cl] += __shfl_down(acc[cl], 8, 64);
        }
        if (lane < 8) {
#pragma unroll
            for (int cl = 0; cl < 10; ++cl) part[wave][lane][cl] = acc[cl];
        }
    }
    __syncthreads();

    // --- finish logits, then log_softmax (40 threads) ---
    if (tid < 40) {
        const int img = tid / 10, cl = tid - (tid / 10) * 10;
        if (img0 + img < B) {
            float lg = bias[cl];
#pragma unroll
            for (int j = 0; j < 8; ++j) lg += part[img][j][cl];
            logits[img][cl] = lg;
        }
    }
    __syncthreads();
    if (tid < 40) {
        const int img = tid / 10, cl = tid - (tid / 10) * 10;
        if (img0 + img < B) {
            float m = -1e30f;
#pragma unroll
            for (int j = 0; j < 10; ++j) m = fmaxf(m, logits[img][j]);
            float ssum = 0.f;
#pragma unroll
            for (int j = 0; j < 10; ++j) ssum += expf(logits[img][j] - m);
            out[(size_t)(img0 + img) * 10 + cl] = logits[img][cl] - m - logf(ssum);
        }
    }
}

extern "C" void kernel_launch(void* const* d_in, const int* in_sizes, int n_in,
                              void* d_out, int out_size, void* d_ws, size_t ws_size,
                              hipStream_t stream) {
    const float* x    = (const float*)d_in[0];
    const float* wts  = (const float*)d_in[1];
    const float* W    = (const float*)d_in[2];
    const float* bias = (const float*)d_in[3];
    float* out        = (float*)d_out;

    const int B = in_sizes[0] / 784;
    const int blocks = (B + 3) / 4;
    quanv4_kernel<<<blocks, 256, 0, stream>>>(x, wts, W, bias, out, B);
}